// Round 1
// 8483.620 us; speedup vs baseline: 1.6059x; 1.6059x over previous
//
#include <hip/hip_runtime.h>

#define NA   50000
#define NP   15000
#define EA   200000
#define EP   60000
#define EC   50000
#define HID  300
#define CH   50000   // edge-chunk rows (even, so pair e^1 stays in-chunk)

#define CDIV(a,b) (((a)+(b)-1)/(b))

typedef __attribute__((ext_vector_type(8))) short short8;
typedef __attribute__((ext_vector_type(4))) float f32x4;

// round-to-nearest-even float -> bf16 bits
__device__ __forceinline__ unsigned short f2bf_rn(float f)
{
    unsigned u = __float_as_uint(f);
    unsigned r = u + 0x7fffu + ((u >> 16) & 1u);
    return (unsigned short)(r >> 16);
}

// ---------------------------------------------------------------------------
// Weight pre-swizzle: W[300][300] fp32 -> hi/lo bf16 in MFMA fragment order.
// Layout: [kstep 0..9][nfrag 0..19][lane 0..63][j 0..7]
//   element = W[32*s + 8*(lane>>4) + j][16*nf + (lane&15)]  (0 if OOB)
// 10*20*64*8 = 102400 ushorts per matrix per (hi|lo).
// ---------------------------------------------------------------------------
__global__ void wswz_kernel(const float* __restrict__ W,
                            unsigned short* __restrict__ Bh,
                            unsigned short* __restrict__ Bl)
{
    int t = blockIdx.x * 256 + threadIdx.x;
    if (t >= 10 * 20 * 64) return;
    int lane = t & 63;
    int f    = t >> 6;        // s*20 + nf
    int nf   = f % 20;
    int s    = f / 20;
    int n    = nf * 16 + (lane & 15);
    int kb   = s * 32 + ((lane >> 4) << 3);
    short8 hv, lv;
#pragma unroll
    for (int j = 0; j < 8; ++j) {
        int k = kb + j;
        float v = (k < 300 && n < 300) ? W[k * 300 + n] : 0.f;
        unsigned u = __float_as_uint(v);
        hv[j] = (short)(u >> 16);                         // truncated high bf16
        float rem = v - __uint_as_float(u & 0xffff0000u); // exact remainder
        lv[j] = (short)f2bf_rn(rem);
    }
    *(short8*)&Bh[(size_t)t * 8] = hv;
    *(short8*)&Bl[(size_t)t * 8] = lv;
}

// ---------------------------------------------------------------------------
// Split-bf16 MFMA GEMM: C[M,300] = act((accum?C:0) + A[M,300]@B + bias + res)
// A fp32 row-major, B pre-swizzled hi/lo bf16 (see wswz_kernel).
// A*B ~= Ahi*Bhi + Ahi*Blo + Alo*Bhi  (fp32 accumulate; rel err ~2^-16)
// Tile 128x160, 256 thr = 4 waves (2x2), wave = 64x80 = 4x5 frags 16x16x32.
// A staged to LDS in fragment-major order (lane-linear, conflict-free).
// ---------------------------------------------------------------------------
__global__ __launch_bounds__(256)
void gemm_mfma_kernel(const float* __restrict__ A,
                      const unsigned short* __restrict__ Bh,
                      const unsigned short* __restrict__ Bl,
                      const float* __restrict__ bias,
                      const float* __restrict__ res,
                      float* __restrict__ C,
                      int M, int accum, int relu)
{
    __shared__ unsigned short Ah[128 * 32];
    __shared__ unsigned short Al[128 * 32];
    const int tid  = threadIdx.x;
    const int lane = tid & 63;
    const int wid  = tid >> 6;
    const int wm   = wid >> 1;
    const int wn   = wid & 1;
    const int row0 = blockIdx.y * 128;
    const int nf0  = blockIdx.x * 10 + wn * 5;   // global n-frag base of wave

    // staging assignment: thread stages row sr, k-octets {so, so+2}
    const int sr   = tid >> 1;
    const int so   = tid & 1;
    const int grow = row0 + sr;
    const bool rv  = (grow < M);
    const float* arow = A + (size_t)grow * 300;
    const int slot_base = (sr >> 4) * 64 + (sr & 15);

    f32x4 acc[4][5];
#pragma unroll
    for (int i = 0; i < 4; ++i)
#pragma unroll
        for (int j = 0; j < 5; ++j)
            acc[i][j] = (f32x4){0.f, 0.f, 0.f, 0.f};

    const float4 z4 = {0.f, 0.f, 0.f, 0.f};
    float4 ra0, ra1, ra2, ra3;

    auto load_stage = [&](int s) {
        int kb = s * 32 + so * 8;
        int kc = kb + 16;
        if (rv) {
            ra0 = (kb + 4 <= 300) ? *(const float4*)(arow + kb)     : z4;
            ra1 = (kb + 8 <= 300) ? *(const float4*)(arow + kb + 4) : z4;
            ra2 = (kc + 4 <= 300) ? *(const float4*)(arow + kc)     : z4;
            ra3 = (kc + 8 <= 300) ? *(const float4*)(arow + kc + 4) : z4;
        } else { ra0 = ra1 = ra2 = ra3 = z4; }
    };

    auto cvt_write = [&](float4 a, float4 b, int o) {
        float v[8] = {a.x, a.y, a.z, a.w, b.x, b.y, b.z, b.w};
        short8 hv, lv;
#pragma unroll
        for (int j = 0; j < 8; ++j) {
            unsigned u = __float_as_uint(v[j]);
            hv[j] = (short)(u >> 16);
            float rem = v[j] - __uint_as_float(u & 0xffff0000u);
            lv[j] = (short)f2bf_rn(rem);
        }
        int slot = slot_base + (o << 4);
        *(short8*)&Ah[slot * 8] = hv;
        *(short8*)&Al[slot * 8] = lv;
    };

    load_stage(0);
    for (int s = 0; s < 10; ++s) {
        cvt_write(ra0, ra1, so);
        cvt_write(ra2, ra3, so + 2);
        if (s < 9) load_stage(s + 1);          // prefetch next A tile into regs

        // B fragments for this k-step: straight from global (L2-resident)
        const unsigned short* bp = Bh + (((size_t)s * 20 + nf0) * 64 + lane) * 8;
        const unsigned short* lp = Bl + (((size_t)s * 20 + nf0) * 64 + lane) * 8;
        short8 bh[5], bl[5];
#pragma unroll
        for (int nf = 0; nf < 5; ++nf) {
            bh[nf] = *(const short8*)(bp + nf * 512);
            bl[nf] = *(const short8*)(lp + nf * 512);
        }
        __syncthreads();

        short8 ah[4], al[4];
#pragma unroll
        for (int mf = 0; mf < 4; ++mf) {
            int slot = (wm * 4 + mf) * 64 + lane;
            ah[mf] = *(const short8*)&Ah[slot * 8];
            al[mf] = *(const short8*)&Al[slot * 8];
        }
#pragma unroll
        for (int mf = 0; mf < 4; ++mf)
#pragma unroll
            for (int nf = 0; nf < 5; ++nf) {
                acc[mf][nf] = __builtin_amdgcn_mfma_f32_16x16x32_bf16(ah[mf], bh[nf], acc[mf][nf], 0, 0, 0);
                acc[mf][nf] = __builtin_amdgcn_mfma_f32_16x16x32_bf16(ah[mf], bl[nf], acc[mf][nf], 0, 0, 0);
                acc[mf][nf] = __builtin_amdgcn_mfma_f32_16x16x32_bf16(al[mf], bh[nf], acc[mf][nf], 0, 0, 0);
            }
        __syncthreads();
    }

    // epilogue: D layout col = lane&15, row = (lane>>4)*4 + reg
    const int rb = row0 + wm * 64 + (lane >> 4) * 4;
    const int cb = nf0 * 16 + (lane & 15);
#pragma unroll
    for (int mf = 0; mf < 4; ++mf) {
        int r0 = rb + mf * 16;
#pragma unroll
        for (int nf = 0; nf < 5; ++nf) {
            int col = cb + nf * 16;
            if (col >= 300) continue;
            float bv = bias ? bias[col] : 0.f;
#pragma unroll
            for (int i = 0; i < 4; ++i) {
                int row = r0 + i;
                if (row >= M) continue;
                size_t o = (size_t)row * 300 + col;
                float v = acc[mf][nf][i] + bv;
                if (res)   v += res[o];
                if (accum) v += C[o];
                if (relu)  v = fmaxf(v, 0.f);
                C[o] = v;
            }
        }
    }
}

// ---------------------------------------------------------------------------
// Elementwise / scatter kernels (unchanged)
// ---------------------------------------------------------------------------
__global__ void deg_kernel(const int* __restrict__ dst, float* __restrict__ deg, int E)
{
    int t = blockIdx.x * blockDim.x + threadIdx.x;
    if (t < E) unsafeAtomicAdd(&deg[dst[t]], 1.f);
}

__global__ void attn_score_kernel(const float* __restrict__ q, const float* __restrict__ k,
                                  const int* __restrict__ dst,
                                  float* __restrict__ es, float* __restrict__ den, int E)
{
    int t = blockIdx.x * blockDim.x + threadIdx.x;
    if (t >= E * 4) return;
    int e = t >> 2;
    int h = t & 3;
    int d = dst[e];
    const float* qp = q + (size_t)d * HID + h * 75;
    const float* kp = k + (size_t)e * HID + h * 75;
    float s = 0.f;
#pragma unroll 5
    for (int i = 0; i < 75; ++i) s = fmaf(qp[i], kp[i], s);
    float ex = expf(s * 0.11547005383792516f);   // 1/sqrt(75)
    es[t] = ex;
    unsafeAtomicAdd(&den[d * 4 + h], ex);
}

__global__ void attn_ctx_kernel(const float* __restrict__ v, const float* __restrict__ es,
                                const float* __restrict__ den, const int* __restrict__ dst,
                                float* __restrict__ ctx, int E)
{
    int t = blockIdx.x * blockDim.x + threadIdx.x;
    if (t >= E * HID) return;
    int e = t / HID;
    int dc = t - e * HID;
    int h = dc / 75;
    int d = dst[e];
    float w = es[e * 4 + h] / den[d * 4 + h];
    unsafeAtomicAdd(&ctx[(size_t)d * HID + dc], w * v[t]);
}

__global__ void masked_residual_kernel(const float* __restrict__ outp,
                                       const float* __restrict__ deg,
                                       float* __restrict__ feat, int total)
{
    int t = blockIdx.x * blockDim.x + threadIdx.x;
    if (t >= total) return;
    int n = t / HID;
    if (deg[n] > 0.f) feat[t] += outp[t];
}

__global__ void gather_sub_kernel(const float* __restrict__ feat, const float* __restrict__ h,
                                  const int* __restrict__ src, float* __restrict__ m,
                                  int mrows, int c0)
{
    int t = blockIdx.x * blockDim.x + threadIdx.x;
    if (t >= mrows * HID) return;
    int el = t / HID;
    int d  = t - el * HID;
    int ge = c0 + el;
    m[t] = feat[(size_t)src[ge] * HID + d] - h[(size_t)(ge ^ 1) * HID + d];
}

__global__ void mail_sum_kernel(const float* __restrict__ h, const int* __restrict__ dst,
                                float* __restrict__ mail, int E)
{
    int t = blockIdx.x * blockDim.x + threadIdx.x;
    if (t >= E * HID) return;
    int e = t / HID;
    int d = t - e * HID;
    unsafeAtomicAdd(&mail[(size_t)dst[e] * HID + d], h[t]);
}

__global__ void mail_gather_kernel(const float* __restrict__ feat, const int* __restrict__ src,
                                   const int* __restrict__ dst, float* __restrict__ mail, int E)
{
    int t = blockIdx.x * blockDim.x + threadIdx.x;
    if (t >= E * HID) return;
    int e = t / HID;
    int d = t - e * HID;
    unsafeAtomicAdd(&mail[(size_t)dst[e] * HID + d], feat[(size_t)src[e] * HID + d]);
}

__global__ void select_kernel(const float* __restrict__ newv, const float* __restrict__ oldv,
                              const float* __restrict__ deg, float* __restrict__ outp, int total)
{
    int t = blockIdx.x * blockDim.x + threadIdx.x;
    if (t >= total) return;
    int n = t / HID;
    outp[t] = (deg[n] > 0.f) ? newv[t] : oldv[t];
}

// ---------------------------------------------------------------------------
// Host-side helpers
// ---------------------------------------------------------------------------
struct Wz { const unsigned short* h; const unsigned short* l; };

static void gemm(const float* A, Wz W, const float* bias, const float* res,
                 float* C, int M, int accum, int relu, hipStream_t s)
{
    dim3 grid(2, CDIV(M, 128));   // N=300 -> 2 col-blocks of 160 (padded 320)
    gemm_mfma_kernel<<<grid, 256, 0, s>>>(A, W.h, W.l, bias, res, C, M, accum, relu);
}

static void run_attn(float* feat, const float* h, const int* dst, int n, int E,
                     Wz q, const float* bq, Wz k, const float* bk,
                     Wz v, const float* bv, Wz o, const float* bo,
                     const float* deg,
                     float* Q, float* KV, float* CTX, float* ES, float* DEN,
                     hipStream_t stream)
{
    gemm(feat, q, bq, nullptr, Q, n, 0, 0, stream);                    // q
    hipMemsetAsync(DEN, 0, (size_t)n * 4 * sizeof(float), stream);
    for (int c0 = 0; c0 < E; c0 += CH) {                               // k + scores
        int m = (E - c0 < CH) ? (E - c0) : CH;
        gemm(h + (size_t)c0 * HID, k, bk, nullptr, KV, m, 0, 0, stream);
        attn_score_kernel<<<CDIV(m * 4, 256), 256, 0, stream>>>(
            Q, KV, dst + c0, ES + (size_t)c0 * 4, DEN, m);
    }
    hipMemsetAsync(CTX, 0, (size_t)n * HID * sizeof(float), stream);
    for (int c0 = 0; c0 < E; c0 += CH) {                               // v + aggregate
        int m = (E - c0 < CH) ? (E - c0) : CH;
        gemm(h + (size_t)c0 * HID, v, bv, nullptr, KV, m, 0, 0, stream);
        attn_ctx_kernel<<<CDIV(m * HID, 256), 256, 0, stream>>>(
            KV, ES + (size_t)c0 * 4, DEN, dst + c0, CTX, m);
    }
    gemm(CTX, o, bo, nullptr, Q, n, 0, 0, stream);                     // out
    masked_residual_kernel<<<CDIV(n * HID, 256), 256, 0, stream>>>(Q, deg, feat, n * HID);
}

static void run_mp(const float* feat, float* h, const float* x, const int* src,
                   Wz W, const float* b, int E, float* MB, hipStream_t stream)
{
    for (int c0 = 0; c0 < E; c0 += CH) {
        int m = (E - c0 < CH) ? (E - c0) : CH;
        gather_sub_kernel<<<CDIV(m * HID, 256), 256, 0, stream>>>(feat, h, src, MB, m, c0);
        gemm(MB, W, b, x + (size_t)c0 * HID, h + (size_t)c0 * HID, m, 0, 1, stream);
    }
}

static void last_pass(const float* mail, const float* mid, const float* first,
                      Wz w0, Wz w1, Wz w2, const float* b, const float* deg,
                      const float* oldv, float* tmp, float* outp, int n, hipStream_t stream)
{
    gemm(mail,  w0, b,       nullptr, tmp, n, 0, 0, stream);
    gemm(mid,   w1, nullptr, nullptr, tmp, n, 1, 0, stream);
    gemm(first, w2, nullptr, nullptr, tmp, n, 1, 0, stream);
    select_kernel<<<CDIV(n * HID, 256), 256, 0, stream>>>(tmp, oldv, deg, outp, n * HID);
}

// ---------------------------------------------------------------------------
extern "C" void kernel_launch(void* const* d_in, const int* in_sizes, int n_in,
                              void* d_out, int out_size, void* d_ws, size_t ws_size,
                              hipStream_t stream)
{
    (void)in_sizes; (void)n_in; (void)out_size; (void)ws_size;

    const float* f_a      = (const float*)d_in[0];
    const float* f_p      = (const float*)d_in[1];
    const float* f_junc_a = (const float*)d_in[2];
    const float* f_junc_p = (const float*)d_in[3];
    const float* x_aba    = (const float*)d_in[4];
    const float* x_prp    = (const float*)d_in[5];
    const float* Wq_aba = (const float*)d_in[6];  const float* bq_aba = (const float*)d_in[7];
    const float* Wk_aba = (const float*)d_in[8];  const float* bk_aba = (const float*)d_in[9];
    const float* Wv_aba = (const float*)d_in[10]; const float* bv_aba = (const float*)d_in[11];
    const float* Wo_aba = (const float*)d_in[12]; const float* bo_aba = (const float*)d_in[13];
    const float* mpW_aba = (const float*)d_in[14]; const float* mpb_aba = (const float*)d_in[15];
    const float* Wq_prp = (const float*)d_in[16]; const float* bq_prp = (const float*)d_in[17];
    const float* Wk_prp = (const float*)d_in[18]; const float* bk_prp = (const float*)d_in[19];
    const float* Wv_prp = (const float*)d_in[20]; const float* bv_prp = (const float*)d_in[21];
    const float* Wo_prp = (const float*)d_in[22]; const float* bo_prp = (const float*)d_in[23];
    const float* mpW_prp = (const float*)d_in[24]; const float* mpb_prp = (const float*)d_in[25];
    const float* Wlast_a = (const float*)d_in[26]; const float* blast_a = (const float*)d_in[27];
    const float* Wlast_p = (const float*)d_in[28]; const float* blast_p = (const float*)d_in[29];
    const int* a_src  = (const int*)d_in[30]; const int* a_dst  = (const int*)d_in[31];
    const int* p_src  = (const int*)d_in[32]; const int* p_dst  = (const int*)d_in[33];
    const int* ap_src = (const int*)d_in[34]; const int* ap_dst = (const int*)d_in[35];
    const int* pa_src = (const int*)d_in[36]; const int* pa_dst = (const int*)d_in[37];

    float* out = (float*)d_out;

    // ---- workspace layout (floats) ----
    float* ws = (float*)d_ws;
    size_t off = 0;
    auto alloc = [&](size_t nf) {
        float* p = ws + off;
        off += (nf + 255) & ~(size_t)255;
        return p;
    };
    float* FA   = alloc((size_t)NA * HID);
    float* FP   = alloc((size_t)NP * HID);
    float* HA   = alloc((size_t)EA * HID);
    float* HP   = alloc((size_t)EP * HID);
    float* Q    = alloc((size_t)NA * HID);
    float* KV   = alloc((size_t)CH * HID);
    float* CTX  = alloc((size_t)NA * HID);
    float* ES   = alloc((size_t)EA * 4);
    float* DEN  = alloc((size_t)NA * 4);
    float* DEGA = alloc(NA);
    float* DEGP = alloc(NP);
    float* DEGPA= alloc(NA);
    float* DEGAP= alloc(NP);
    // swizzled split-bf16 weights: 18 slices x 102400 ushorts, hi + lo
    unsigned short* SWH = (unsigned short*)alloc(18 * 102400 / 2);
    unsigned short* SWL = (unsigned short*)alloc(18 * 102400 / 2);

    // ---- pre-swizzle all 18 weight slices (300x300 each) ----
    const float* wsrc[18] = {
        Wq_aba, Wk_aba, Wv_aba, Wo_aba,
        Wq_prp, Wk_prp, Wv_prp, Wo_prp,
        mpW_aba, mpW_aba + 90000, mpW_prp, mpW_prp + 90000,
        Wlast_a, Wlast_a + 90000, Wlast_a + 180000,
        Wlast_p, Wlast_p + 90000, Wlast_p + 180000
    };
    for (int i = 0; i < 18; ++i)
        wswz_kernel<<<50, 256, 0, stream>>>(wsrc[i],
                                            SWH + (size_t)i * 102400,
                                            SWL + (size_t)i * 102400);
    auto wz = [&](int i) { return Wz{SWH + (size_t)i * 102400, SWL + (size_t)i * 102400}; };

    // ---- degrees ----
    hipMemsetAsync(DEGA, 0, NA * sizeof(float), stream);
    hipMemsetAsync(DEGP, 0, NP * sizeof(float), stream);
    hipMemsetAsync(DEGPA, 0, NA * sizeof(float), stream);
    hipMemsetAsync(DEGAP, 0, NP * sizeof(float), stream);
    deg_kernel<<<CDIV(EA, 256), 256, 0, stream>>>(a_dst, DEGA, EA);
    deg_kernel<<<CDIV(EP, 256), 256, 0, stream>>>(p_dst, DEGP, EP);
    deg_kernel<<<CDIV(EC, 256), 256, 0, stream>>>(pa_dst, DEGPA, EC);
    deg_kernel<<<CDIV(EC, 256), 256, 0, stream>>>(ap_dst, DEGAP, EC);

    // ---- init state ----
    hipMemcpyAsync(FA, f_a,   (size_t)NA * HID * sizeof(float), hipMemcpyDeviceToDevice, stream);
    hipMemcpyAsync(FP, f_p,   (size_t)NP * HID * sizeof(float), hipMemcpyDeviceToDevice, stream);
    hipMemcpyAsync(HA, x_aba, (size_t)EA * HID * sizeof(float), hipMemcpyDeviceToDevice, stream);
    hipMemcpyAsync(HP, x_prp, (size_t)EP * HID * sizeof(float), hipMemcpyDeviceToDevice, stream);

    // ---- DEPTH-1 = 2 message-passing iterations ----
    for (int i = 0; i < 2; ++i) {
        run_attn(FA, HA, a_dst, NA, EA,
                 wz(0), bq_aba, wz(1), bk_aba, wz(2), bv_aba, wz(3), bo_aba,
                 DEGA, Q, KV, CTX, ES, DEN, stream);
        run_attn(FP, HP, p_dst, NP, EP,
                 wz(4), bq_prp, wz(5), bk_prp, wz(6), bv_prp, wz(7), bo_prp,
                 DEGP, Q, KV, CTX, ES, DEN, stream);
        run_mp(FA, HA, x_aba, a_src, wz(8 + i), mpb_aba + i * HID, EA, KV, stream);
        run_mp(FP, HP, x_prp, p_src, wz(10 + i), mpb_prp + i * HID, EP, KV, stream);
    }

    // ---- final homo pass: fa ----
    hipMemsetAsync(CTX, 0, (size_t)NA * HID * sizeof(float), stream);
    mail_sum_kernel<<<CDIV(EA * HID, 256), 256, 0, stream>>>(HA, a_dst, CTX, EA);
    last_pass(CTX, FA, f_a, wz(12), wz(13), wz(14), blast_a, DEGA, FA, Q, out, NA, stream);

    // ---- final homo pass: fp ----
    hipMemsetAsync(CTX, 0, (size_t)NP * HID * sizeof(float), stream);
    mail_sum_kernel<<<CDIV(EP * HID, 256), 256, 0, stream>>>(HP, p_dst, CTX, EP);
    last_pass(CTX, FP, f_p, wz(15), wz(16), wz(17), blast_p, DEGP, FP, Q,
              out + (size_t)NA * HID, NP, stream);

    // ---- junction pass: fjp ----
    hipMemsetAsync(CTX, 0, (size_t)NP * HID * sizeof(float), stream);
    mail_gather_kernel<<<CDIV(EC * HID, 256), 256, 0, stream>>>(f_junc_a, ap_src, ap_dst, CTX, EC);
    last_pass(CTX, f_junc_p, f_p, wz(15), wz(16), wz(17), blast_p, DEGAP, f_junc_p, Q,
              out + (size_t)(2 * NA + NP) * HID, NP, stream);

    // ---- junction pass: fja ----
    hipMemsetAsync(CTX, 0, (size_t)NA * HID * sizeof(float), stream);
    mail_gather_kernel<<<CDIV(EC * HID, 256), 256, 0, stream>>>(f_junc_p, pa_src, pa_dst, CTX, EC);
    last_pass(CTX, f_junc_a, f_a, wz(12), wz(13), wz(14), blast_a, DEGPA, f_junc_a, Q,
              out + (size_t)(NA + NP) * HID, NA, stream);
}